// Round 6
// baseline (290.147 us; speedup 1.0000x reference)
//
#include <hip/hip_runtime.h>

#define N_NODES 100000
#define HID 64
#define N_EDGES 1600000
#define NB 391                 // ceil(N_NODES / 256) buckets of 256 nodes
#define NBP 392                // padded hist row (partial-hist stride)
#define NHB 256                // histogram blocks
#define C_EPB 6400             // edges per block in bucket_scatter (250 blocks)
#define GATHER_BLOCKS 6250     // N_NODES*16/256 gather blocks in fused prep kernel

typedef __attribute__((ext_vector_type(8))) short bf16x8;
typedef __attribute__((ext_vector_type(4))) float f32x4;

// ---- bf16 helpers (manual, RNE) ------------------------------------------
__device__ __forceinline__ unsigned short f2bf(float f) {
    unsigned u = __float_as_uint(f);
    u = (u + 0x7FFFu + ((u >> 16) & 1u)) >> 16;
    return (unsigned short)u;
}
__device__ __forceinline__ float bflo(unsigned w) { return __uint_as_float(w << 16); }
__device__ __forceinline__ float bfhi(unsigned w) { return __uint_as_float(w & 0xFFFF0000u); }

// ------------------------------------- prep: gather->bf16 + hist + weight pack
// Blocks [0, GATHER_BLOCKS): xh = bf16(emb[node_id]).
// Blocks [GATHER_BLOCKS, +NHB): per-block partial dst-bucket histograms.
// Blocks [GATHER_BLOCKS+NHB, +2): pack layer-L weights into lane-ordered bf16
// MFMA fragments: wpack[L][mat*512 + ks*256 + ct*64 + lane][8 shorts], so the
// fused kernel loads each B-fragment as one coalesced 16B L1-hit.
__global__ void prep_kernel(const float* __restrict__ emb,
                            const int* __restrict__ nid,
                            unsigned short* __restrict__ xh,
                            const int* __restrict__ dst,
                            int* __restrict__ bhist_part,
                            const float* __restrict__ Wl1,
                            const float* __restrict__ Wr1,
                            const float* __restrict__ Wl2,
                            const float* __restrict__ Wr2,
                            unsigned short* __restrict__ wpack) {
    if (blockIdx.x < GATHER_BLOCKS) {
        int i = blockIdx.x * blockDim.x + threadIdx.x;
        const int total = N_NODES * (HID / 4);
        if (i >= total) return;
        int row = i >> 4;
        int c   = i & 15;
        int s   = nid[row];
        float4 v = reinterpret_cast<const float4*>(emb)[(size_t)s * 16 + c];
        uint2 p;
        p.x = (unsigned)f2bf(v.x) | ((unsigned)f2bf(v.y) << 16);
        p.y = (unsigned)f2bf(v.z) | ((unsigned)f2bf(v.w) << 16);
        reinterpret_cast<uint2*>(xh)[(size_t)row * 16 + c] = p;
        return;
    }
    if (blockIdx.x < GATHER_BLOCKS + NHB) {
        // ---- histogram part (NHB blocks)
        __shared__ int h[NB];
        for (int i = threadIdx.x; i < NB; i += blockDim.x) h[i] = 0;
        __syncthreads();
        int hb = blockIdx.x - GATHER_BLOCKS;
        const int nt = NHB * 256;
        const int4* d4 = (const int4*)dst;
        for (int q = hb * blockDim.x + threadIdx.x; q < N_EDGES / 4; q += nt) {
            int4 v = d4[q];
            atomicAdd(&h[v.x >> 8], 1);
            atomicAdd(&h[v.y >> 8], 1);
            atomicAdd(&h[v.z >> 8], 1);
            atomicAdd(&h[v.w >> 8], 1);
        }
        __syncthreads();
        for (int i = threadIdx.x; i < NB; i += blockDim.x)
            bhist_part[hb * NBP + i] = h[i];
        return;
    }
    // ---- weight pack (2 blocks, one per layer)
    int L = blockIdx.x - GATHER_BLOCKS - NHB;        // 0 or 1
    const float* WL = L ? Wl2 : Wl1;
    const float* WR = L ? Wr2 : Wr1;
    for (int idx = threadIdx.x; idx < 1024; idx += 256) {
        int lane = idx & 63;
        int ct   = (idx >> 6) & 3;
        int ks   = (idx >> 8) & 1;
        int mat  = idx >> 9;
        const float* W = mat ? WR : WL;
        int m = lane & 15, quad = lane >> 4;
        const float* p = W + (ct * 16 + m) * HID + ks * 32 + quad * 8;
        unsigned short* q = wpack + ((size_t)L * 1024 + idx) * 8;
        #pragma unroll
        for (int j = 0; j < 8; ++j) q[j] = f2bf(p[j]);
    }
}

// ---------------------------------------------------------------- CSR build, pass B
__global__ void bucket_scan(const int* __restrict__ bhist_part,
                            int* __restrict__ boff,
                            int* __restrict__ bcursor) {
    __shared__ int s[512];
    int v = 0;
    if (threadIdx.x < NB) {
        #pragma unroll 8
        for (int p = 0; p < NHB; ++p) v += bhist_part[p * NBP + threadIdx.x];
    }
    s[threadIdx.x] = v;
    __syncthreads();
    for (int off = 1; off < 512; off <<= 1) {
        int t = (threadIdx.x >= off) ? s[threadIdx.x - off] : 0;
        __syncthreads();
        s[threadIdx.x] += t;
        __syncthreads();
    }
    if (threadIdx.x < NB) {
        int ex = s[threadIdx.x] - v;
        boff[threadIdx.x] = ex;
        bcursor[threadIdx.x] = ex;
    }
}

// ---------------------------------------------------------------- CSR build, pass C
__global__ void bucket_scatter(const int* __restrict__ src,
                               const int* __restrict__ dst,
                               int* __restrict__ bcursor,
                               int2* __restrict__ pairs) {
    __shared__ int h[NB];
    __shared__ int base[NB];
    for (int i = threadIdx.x; i < NB; i += blockDim.x) h[i] = 0;
    __syncthreads();
    int e0 = blockIdx.x * C_EPB;
    int e1 = e0 + C_EPB; if (e1 > N_EDGES) e1 = N_EDGES;
    for (int e = e0 + threadIdx.x; e < e1; e += blockDim.x)
        atomicAdd(&h[dst[e] >> 8], 1);
    __syncthreads();
    for (int i = threadIdx.x; i < NB; i += blockDim.x) {
        int c = h[i];
        base[i] = c ? atomicAdd(&bcursor[i], c) : 0;
    }
    __syncthreads();
    for (int i = threadIdx.x; i < NB; i += blockDim.x) h[i] = 0;
    __syncthreads();
    for (int e = e0 + threadIdx.x; e < e1; e += blockDim.x) {
        int d = dst[e];
        int b = d >> 8;
        int slot = base[b] + atomicAdd(&h[b], 1);
        pairs[slot] = make_int2(src[e], d);
    }
}

// ---------------------------------------------------------------- CSR build, pass D
__global__ void bucket_csr(const int2* __restrict__ pairs,
                           const int* __restrict__ boff,
                           const int* __restrict__ bcursor,
                           int* __restrict__ row_start,
                           int* __restrict__ adj) {
    __shared__ int cnt[256];
    __shared__ int sc[256];
    int b = blockIdx.x;
    int node0 = b << 8;
    int p0 = boff[b];
    int p1 = bcursor[b];           // after pass C, bcursor[b] = end of bucket b
    int t = threadIdx.x;
    cnt[t] = 0;
    __syncthreads();
    for (int p = p0 + t; p < p1; p += 256)
        atomicAdd(&cnt[pairs[p].y & 255], 1);
    __syncthreads();
    int v = cnt[t];
    sc[t] = v;
    __syncthreads();
    for (int off = 1; off < 256; off <<= 1) {
        int u = (t >= off) ? sc[t - off] : 0;
        __syncthreads();
        sc[t] += u;
        __syncthreads();
    }
    sc[t] = p0 + sc[t] - v;        // exclusive scan + bucket base = row_start
    __syncthreads();
    int node = node0 + t;
    if (node <= N_NODES) row_start[node] = sc[t];
    __syncthreads();               // row_start read before atomics mutate sc
    for (int p = p0 + t; p < p1; p += 256) {
        int2 pr = pairs[p];
        int slot = atomicAdd(&sc[pr.y & 255], 1);
        adj[slot] = pr.x;
    }
}

// ------------------------------------------------- fused SAGE layer (agg+GEMM)
// One wave owns one 16-row output tile. Agg phase: 16 rows x 4 lanes/row,
// lane (m,quad) accumulates features {quad*8..+7} and {32+quad*8..+7} of row
// t*16+m -- i.e. the mean-agg lands ALREADY in MFMA A-fragment layout, so M
// is never materialized (saves 51 MB of HBM traffic + 2 dispatches vs the
// separate agg+gemm pipeline). 4 neighbors x 2 uint4 = 128B/lane in flight.
// Weights come from wpack as coalesced 16B fragment loads (L1-resident 16KB)
// so no 128-VGPR weight array throttles the gather phase's occupancy.
__global__ void sage_fused_kernel(const int* __restrict__ row_start,
                                  const int* __restrict__ adj,
                                  const unsigned short* __restrict__ X,
                                  const unsigned short* __restrict__ wpack,
                                  const float* __restrict__ bias,
                                  unsigned short* __restrict__ H,
                                  int relu) {
    int lane = threadIdx.x & 63;
    int m    = lane & 15;               // row within tile
    int quad = lane >> 4;               // k-chunk (features quad*8.., 32+quad*8..)
    int wpb = blockDim.x >> 6;
    int wid = blockIdx.x * wpb + (threadIdx.x >> 6);
    int stride = gridDim.x * wpb;
    const int NT = N_NODES / 16;        // 6250
    const uint4* xw = (const uint4*)X;  // row stride = 8 uint4
    const bf16x8* wp = (const bf16x8*)wpack;
    float bv[4];
    #pragma unroll
    for (int ct = 0; ct < 4; ++ct) bv[ct] = bias[ct * 16 + m];

    for (int t = wid; t < NT; t += stride) {
        int row = t * 16 + m;
        int beg = row_start[row], end = row_start[row + 1];
        // ---- aggregation into fragment-layout registers
        float a0 = 0.f, a1 = 0.f, a2 = 0.f, a3 = 0.f;   // ks=0: feats quad*8..+7
        float a4 = 0.f, a5 = 0.f, a6 = 0.f, a7 = 0.f;
        float b0 = 0.f, b1 = 0.f, b2 = 0.f, b3 = 0.f;   // ks=1: feats 32+quad*8..
        float b4 = 0.f, b5 = 0.f, b6 = 0.f, b7 = 0.f;
        int j = beg;
        for (; j + 3 < end; j += 4) {     // 8 uint4 gathers in flight (128B/lane)
            int s0 = adj[j], s1 = adj[j + 1], s2 = adj[j + 2], s3 = adj[j + 3];
            uint4 u0 = xw[(size_t)s0 * 8 + quad];
            uint4 v0 = xw[(size_t)s0 * 8 + 4 + quad];
            uint4 u1 = xw[(size_t)s1 * 8 + quad];
            uint4 v1 = xw[(size_t)s1 * 8 + 4 + quad];
            uint4 u2 = xw[(size_t)s2 * 8 + quad];
            uint4 v2 = xw[(size_t)s2 * 8 + 4 + quad];
            uint4 u3 = xw[(size_t)s3 * 8 + quad];
            uint4 v3 = xw[(size_t)s3 * 8 + 4 + quad];
            a0 += bflo(u0.x) + bflo(u1.x) + bflo(u2.x) + bflo(u3.x);
            a1 += bfhi(u0.x) + bfhi(u1.x) + bfhi(u2.x) + bfhi(u3.x);
            a2 += bflo(u0.y) + bflo(u1.y) + bflo(u2.y) + bflo(u3.y);
            a3 += bfhi(u0.y) + bfhi(u1.y) + bfhi(u2.y) + bfhi(u3.y);
            a4 += bflo(u0.z) + bflo(u1.z) + bflo(u2.z) + bflo(u3.z);
            a5 += bfhi(u0.z) + bfhi(u1.z) + bfhi(u2.z) + bfhi(u3.z);
            a6 += bflo(u0.w) + bflo(u1.w) + bflo(u2.w) + bflo(u3.w);
            a7 += bfhi(u0.w) + bfhi(u1.w) + bfhi(u2.w) + bfhi(u3.w);
            b0 += bflo(v0.x) + bflo(v1.x) + bflo(v2.x) + bflo(v3.x);
            b1 += bfhi(v0.x) + bfhi(v1.x) + bfhi(v2.x) + bfhi(v3.x);
            b2 += bflo(v0.y) + bflo(v1.y) + bflo(v2.y) + bflo(v3.y);
            b3 += bfhi(v0.y) + bfhi(v1.y) + bfhi(v2.y) + bfhi(v3.y);
            b4 += bflo(v0.z) + bflo(v1.z) + bflo(v2.z) + bflo(v3.z);
            b5 += bfhi(v0.z) + bfhi(v1.z) + bfhi(v2.z) + bfhi(v3.z);
            b6 += bflo(v0.w) + bflo(v1.w) + bflo(v2.w) + bflo(v3.w);
            b7 += bfhi(v0.w) + bfhi(v1.w) + bfhi(v2.w) + bfhi(v3.w);
        }
        for (; j < end; ++j) {
            int s = adj[j];
            uint4 u = xw[(size_t)s * 8 + quad];
            uint4 v = xw[(size_t)s * 8 + 4 + quad];
            a0 += bflo(u.x); a1 += bfhi(u.x); a2 += bflo(u.y); a3 += bfhi(u.y);
            a4 += bflo(u.z); a5 += bfhi(u.z); a6 += bflo(u.w); a7 += bfhi(u.w);
            b0 += bflo(v.x); b1 += bfhi(v.x); b2 += bflo(v.y); b3 += bfhi(v.y);
            b4 += bflo(v.z); b5 += bfhi(v.z); b6 += bflo(v.w); b7 += bfhi(v.w);
        }
        float inv = 1.0f / fmaxf((float)(end - beg), 1.0f);
        // mean -> bf16 A-fragments (same f2bf rounding as the old M path)
        bf16x8 am0, am1;
        am0[0] = (short)f2bf(a0 * inv); am0[1] = (short)f2bf(a1 * inv);
        am0[2] = (short)f2bf(a2 * inv); am0[3] = (short)f2bf(a3 * inv);
        am0[4] = (short)f2bf(a4 * inv); am0[5] = (short)f2bf(a5 * inv);
        am0[6] = (short)f2bf(a6 * inv); am0[7] = (short)f2bf(a7 * inv);
        am1[0] = (short)f2bf(b0 * inv); am1[1] = (short)f2bf(b1 * inv);
        am1[2] = (short)f2bf(b2 * inv); am1[3] = (short)f2bf(b3 * inv);
        am1[4] = (short)f2bf(b4 * inv); am1[5] = (short)f2bf(b5 * inv);
        am1[6] = (short)f2bf(b6 * inv); am1[7] = (short)f2bf(b7 * inv);
        // self features, directly in fragment layout
        bf16x8 as0 = *(const bf16x8*)(X + (size_t)row * HID + quad * 8);
        bf16x8 as1 = *(const bf16x8*)(X + (size_t)row * HID + 32 + quad * 8);
        // ---- MFMA: out = Wl @ mean + Wr @ self  (B-fragments from wpack, L1)
        f32x4 acc[4] = {{0,0,0,0},{0,0,0,0},{0,0,0,0},{0,0,0,0}};
        #pragma unroll
        for (int ks = 0; ks < 2; ++ks) {
            bf16x8 amean = ks ? am1 : am0;
            bf16x8 aself = ks ? as1 : as0;
            #pragma unroll
            for (int ct = 0; ct < 4; ++ct) {
                acc[ct] = __builtin_amdgcn_mfma_f32_16x16x32_bf16(
                    amean, wp[(size_t)ks * 256 + ct * 64 + lane], acc[ct], 0, 0, 0);
                acc[ct] = __builtin_amdgcn_mfma_f32_16x16x32_bf16(
                    aself, wp[(size_t)512 + ks * 256 + ct * 64 + lane], acc[ct], 0, 0, 0);
            }
        }
        #pragma unroll
        for (int ct = 0; ct < 4; ++ct) {
            #pragma unroll
            for (int r = 0; r < 4; ++r) {
                float v = acc[ct][r] + bv[ct];
                if (relu) v = fmaxf(v, 0.f);
                H[((size_t)t * 16 + quad * 4 + r) * HID + ct * 16 + m] = f2bf(v);
            }
        }
    }
}

// ---------------------------------------------------------------- edge dot (bf16)
// Flat edge-order form (measured 43.1us at the 3.64 TB/s fetch-path ceiling):
// 8 lanes per 2 consecutive edges, 4 uint4 gathers in flight/lane,
// coalesced float2 output write. No per-row loop -> MLP never collapses.
__global__ void edge_dot_kernel(const int* __restrict__ src,
                                const int* __restrict__ dst,
                                const unsigned short* __restrict__ h,
                                float* __restrict__ out) {
    int t = blockIdx.x * blockDim.x + threadIdx.x;
    int g = t >> 3;                 // edge-pair group
    int c = t & 7;
    int e0 = g * 2;
    if (e0 >= N_EDGES) return;
    int a0 = src[e0],     b0 = dst[e0];
    int a1 = src[e0 + 1], b1 = dst[e0 + 1];
    const uint4* h4 = reinterpret_cast<const uint4*>(h);
    uint4 va0 = h4[(size_t)a0 * 8 + c];
    uint4 vb0 = h4[(size_t)b0 * 8 + c];
    uint4 va1 = h4[(size_t)a1 * 8 + c];
    uint4 vb1 = h4[(size_t)b1 * 8 + c];
    float p0 = bflo(va0.x) * bflo(vb0.x) + bfhi(va0.x) * bfhi(vb0.x)
             + bflo(va0.y) * bflo(vb0.y) + bfhi(va0.y) * bfhi(vb0.y)
             + bflo(va0.z) * bflo(vb0.z) + bfhi(va0.z) * bfhi(vb0.z)
             + bflo(va0.w) * bflo(vb0.w) + bfhi(va0.w) * bfhi(vb0.w);
    float p1 = bflo(va1.x) * bflo(vb1.x) + bfhi(va1.x) * bfhi(vb1.x)
             + bflo(va1.y) * bflo(vb1.y) + bfhi(va1.y) * bfhi(vb1.y)
             + bflo(va1.z) * bflo(vb1.z) + bfhi(va1.z) * bfhi(vb1.z)
             + bflo(va1.w) * bflo(vb1.w) + bfhi(va1.w) * bfhi(vb1.w);
    p0 += __shfl_xor(p0, 1); p0 += __shfl_xor(p0, 2); p0 += __shfl_xor(p0, 4);
    p1 += __shfl_xor(p1, 1); p1 += __shfl_xor(p1, 2); p1 += __shfl_xor(p1, 4);
    if (c == 0) reinterpret_cast<float2*>(out)[g] = make_float2(p0, p1);
}

extern "C" void kernel_launch(void* const* d_in, const int* in_sizes, int n_in,
                              void* d_out, int out_size, void* d_ws, size_t ws_size,
                              hipStream_t stream) {
    const float* emb = (const float*)d_in[0];
    const float* Wl1 = (const float*)d_in[1];
    const float* Wr1 = (const float*)d_in[2];
    const float* b1  = (const float*)d_in[3];
    const float* Wl2 = (const float*)d_in[4];
    const float* Wr2 = (const float*)d_in[5];
    const float* b2  = (const float*)d_in[6];
    const int*   nid = (const int*)d_in[7];
    const int*   ei  = (const int*)d_in[8];
    const int* esrc = ei;
    const int* edst = ei + N_EDGES;
    float* out = (float*)d_out;

    const size_t NH = (size_t)N_NODES * HID;   // 6.4M elements
    unsigned short* xh  = (unsigned short*)d_ws;          // [N,64] bf16
    unsigned short* h1h = xh + NH;                        // [N,64] bf16
    unsigned short* h2h = h1h + NH;                       // [N,64] bf16
    int* ib        = (int*)(h2h + NH);                    // int region
    int* row_start = ib;                          // [N+1]
    int* adj       = ib + N_NODES + 64;           // [E]
    int2* pairs    = (int2*)(adj + N_EDGES + 64); // [E] (src,dst)
    int* bhist_part = (int*)(pairs + N_EDGES);    // [NHB*NBP] partial hists
    int* boff      = bhist_part + NHB * NBP;      // [NB]
    int* bcursor   = boff + NB + 1;               // [NB]
    unsigned short* wpack = (unsigned short*)(bcursor + NB + 1); // [2][1024][8]

    // fused: xh = bf16(emb[node_id]) + partial histograms + weight pack
    prep_kernel<<<GATHER_BLOCKS + NHB + 2, 256, 0, stream>>>(
        emb, nid, xh, edst, bhist_part, Wl1, Wr1, Wl2, Wr2, wpack);

    // ---- CSR build via bucket counting sort (shared by both layers)
    bucket_scan<<<1, 512, 0, stream>>>(bhist_part, boff, bcursor);
    bucket_scatter<<<(N_EDGES + C_EPB - 1) / C_EPB, 256, 0, stream>>>(esrc, edst, bcursor, pairs);
    bucket_csr<<<NB, 256, 0, stream>>>(pairs, boff, bcursor, row_start, adj);

    // ---- fused SAGE layers: agg (fragment-layout) + MFMA in one kernel
    sage_fused_kernel<<<1563, 256, 0, stream>>>(row_start, adj, xh,
                                                wpack, b1, h1h, 1);
    sage_fused_kernel<<<1563, 256, 0, stream>>>(row_start, adj, h1h,
                                                wpack + 1024 * 8, b2, h2h, 0);

    // ---- edge classifier on bf16 features (flat edge-order, at path ceiling)
    edge_dot_kernel<<<((size_t)(N_EDGES / 2) * 8 + 255) / 256, 256, 0, stream>>>(esrc, edst, h2h, out);
}